// Round 9
// baseline (229.324 us; speedup 1.0000x reference)
//
#include <hip/hip_runtime.h>

// ---------------------------------------------------------------------------
// ConvCaps (EM routing): b=8, B=32, C=32, K=3, stride=2, Win=13, Wout=6, 3 iters
// x: (8, 544, 13, 13) f32   [pose 512ch = (q,r,o), act 32ch]
// W: (3,3,32,32,4,4) f32    [ch=(ij*32+o)][c][p][q], 512 floats per ch
// out: (8, 544, 6, 6) f32
// vote[d=p*4+r] = sum_q W[ch][c][p][q] * pose[n,q,r,o, 2x+i, 2y+j]
//
// Fused M+E kernel: grid = 2304 blocks = 8 c_grps x 288 spatials. Wave = one c.
// R8 lesson: residency was LDS-limited (29 KB/block -> ~2.2 blocks/CU no
// matter the launch bounds). R9: NO pose/act LDS staging at all — posT2 is
// re-laid out [n][pix][o][d] so the M/E loops read it directly from global
// with half-wave-contiguous 2 KB segments (L2-resident, 2.8 MB); act/D are
// per-lane coalesced 4 B loads. Only sPh (4.6 KB) remains in LDS for the
// cross-wave D reduction. W from Wt2[c][ch][16], lane-contiguous.
// votesE == votes (kperm only permutes output slot); E recomputes votes.
// p_hat slices are block-private; only D crosses blocks -> ping-pong D0/D1.
// ---------------------------------------------------------------------------

// workspace layout (floats)
#define OFF_PHAT 0           // 288*32*288 = 2654208   [spatial][c][slot]
#define OFF_D0   2654208     // 43264 = 8*169*32   [n][pix][o]
#define OFF_D1   2697472     // 43264
#define OFF_POST 2740736     // 692224 = 8*169*32*16   [n][pix][o][d]
#define OFF_ACTT 3432960     // 43264  [n][pix][o]
#define OFF_WT2  3476224     // 147456 = 32*288*16  [c][ch][d]
// total 3623680 floats = 14.5 MB

__device__ __forceinline__ float wred64(float v) {
#pragma unroll
  for (int m = 32; m >= 1; m >>= 1) v += __shfl_xor(v, m, 64);
  return v;
}

__device__ __forceinline__ void load16(const float* __restrict__ p, float* dst) {
  const float4* p4 = (const float4*)p;
  float4 a = p4[0], b = p4[1], c = p4[2], d = p4[3];
  dst[0]=a.x; dst[1]=a.y; dst[2]=a.z; dst[3]=a.w;
  dst[4]=b.x; dst[5]=b.y; dst[6]=b.z; dst[7]=b.w;
  dst[8]=c.x; dst[9]=c.y; dst[10]=c.z; dst[11]=c.w;
  dst[12]=d.x; dst[13]=d.y; dst[14]=d.z; dst[15]=d.w;
}

// One fused prep kernel (range-branched elementwise):
//   [0,692224)        pose transpose -> posT2[n][pix][o][d]
//   [692224,735488)   act transpose  -> actT[n][pix][o]
//   [735488,882944)   W transpose    -> Wt2[c][ch][d]
//   [882944,969472)   zero D0 and D1
__global__ __launch_bounds__(256) void prep_kernel(
    const float* __restrict__ x, const float* __restrict__ Wt,
    float* __restrict__ posT2, float* __restrict__ actT,
    float* __restrict__ Wt2, float* __restrict__ Dz) {
  int tid = blockIdx.x * 256 + threadIdx.x;   // 969472 = 3787*256
  if (tid < 692224) {
    int pix = tid % 169; int t = tid / 169;
    int o = t & 31; t >>= 5;
    int d = t & 15; int n = t >> 4;
    float v = x[((size_t)n * 544 + d * 32 + o) * 169 + pix];
    posT2[(((size_t)n * 169 + pix) * 32 + o) * 16 + d] = v;
  } else if (tid < 735488) {
    int r = tid - 692224;
    int pix = r % 169; int t = r / 169;
    int o = t & 31; int n = t >> 5;
    float v = x[(size_t)n * 91936 + 86528 + o * 169 + pix];
    actT[((size_t)n * 169 + pix) * 32 + o] = v;
  } else if (tid < 882944) {
    int r = tid - 735488;                     // 147456 = 32*288*16
    int c = r / 4608; int s = r - c * 4608;
    int ch = s >> 4, d = s & 15;
    Wt2[r] = Wt[(size_t)ch * 512 + c * 16 + d];
  } else {
    Dz[tid - 882944] = 0.f;                   // D0 then D1 (contiguous)
  }
}

// Fused EM step.
// mode 0: M(uniform Rp) + E -> p_hat, Dwrite
// mode 1: M(p_hat, Dread) + E -> p_hat, Dwrite
// mode 2: M(p_hat, Dread) -> final output
__global__ __launch_bounds__(256, 3) void em_kernel(
    const float* __restrict__ Wt2, const float* __restrict__ posT2,
    const float* __restrict__ actT, float* __restrict__ p_hat,
    const float* __restrict__ Dread, float* __restrict__ Dwrite,
    const float* __restrict__ beta_v, const float* __restrict__ beta_a,
    const float* __restrict__ lambda_, float* __restrict__ out, int mode) {
  __shared__ float sPh[4 * 288];   // per-wave p_hat by slot, for D reduce

  const int g = blockIdx.x & 7;        // c group
  const int sg = blockIdx.x >> 3;      // spatial 0..287
  const int wave = threadIdx.x >> 6;
  const int lane = threadIdx.x & 63;
  const int c = g * 4 + wave;

  int t = sg;
  const int y = t % 6; t /= 6;
  const int xx = t % 6;
  const int n = t / 6;

  const float bvv = beta_v[0], bav = beta_a[0], lamv = lambda_[0];
  const float* wbase = Wt2 + (size_t)c * 4608;
  const float* phb = p_hat + ((size_t)sg * 32 + c) * 288;

  // per-lane child geometry for each k chunk: ch = lane + 64k = ij*32 + o
  const int o = lane & 31;
  const int ijbase = lane >> 5;        // ij = ijbase + 2k

  // ---- M step: direct coalesced global reads, no LDS staging ----
  float sum_r = 0.f, sv[16], sq[16];
#pragma unroll
  for (int d = 0; d < 16; ++d) { sv[d] = 0.f; sq[d] = 0.f; }

#pragma unroll
  for (int k = 0; k < 5; ++k) {
    const int ch = lane + 64 * k;
    const bool act_l = (ch < 288);
    const int ij = act_l ? (ijbase + 2 * k) : 0;
    const int i = ij / 3, j = ij - i * 3;
    const int idx = ((n * 169 + (2 * xx + i) * 13 + (2 * y + j)) * 32) + o;

    float P[16], Wm[16];
    load16(posT2 + (size_t)idx * 16, P);
    load16(wbase + (act_l ? ch : 0) * 16, Wm);
    float a = actT[idx];
    float rhat;
    if (mode == 0) {
      rhat = a * (1.0f / 1152.0f);
    } else {
      float ph = phb[act_l ? ch : 0];
      rhat = ph * a * __builtin_amdgcn_rcpf(Dread[idx]);
    }
    if (!act_l) rhat = 0.f;
    sum_r += rhat;
#pragma unroll
    for (int p = 0; p < 4; ++p)
#pragma unroll
      for (int r = 0; r < 4; ++r) {
        float v = Wm[p * 4 + 0] * P[0 + r] + Wm[p * 4 + 1] * P[4 + r] +
                  Wm[p * 4 + 2] * P[8 + r] + Wm[p * 4 + 3] * P[12 + r];
        sv[p * 4 + r] = fmaf(rhat, v, sv[p * 4 + r]);
        sq[p * 4 + r] = fmaf(rhat * v, v, sq[p * 4 + r]);
      }
  }

  sum_r = wred64(sum_r);
  const float inv_sr = 1.0f / sum_r;
  float mu[16];
  float lsum = 0.f;
#pragma unroll
  for (int d = 0; d < 16; ++d) {
    float s1 = wred64(sv[d]);
    float s2 = wred64(sq[d]);
    float m = s1 * inv_sr;
    mu[d] = m;
    float sg_ = fmaxf(s2 * inv_sr - m * m, 1e-30f);
    lsum += __logf(sg_);
  }
  const float cost = (16.f * bvv + lsum) * sum_r;
  const float aout = 1.0f / (1.0f + __expf(-lamv * (bav - cost)));

  if (mode == 2) {
    if (lane == 0) {
      float* ob = out + (size_t)(n * 544 + c * 16) * 36 + xx * 6 + y;
#pragma unroll
      for (int d = 0; d < 16; ++d) ob[d * 36] = mu[d];
      out[(size_t)(n * 544 + 512 + c) * 36 + xx * 6 + y] = aout;
    }
    return;
  }

  // ---- E step: recompute votes (direct global reads again) ----
  const float G = __logf(aout) - 0.5f * (lsum + 16.f * 1.8378770664093453f);
#pragma unroll
  for (int k = 0; k < 5; ++k) {
    const int mch = lane + 64 * k;
    if (mch < 288) {
      const int ijm = ijbase + 2 * k;
      const int im = ijm / 3, jm = ijm - im * 3;
      const int i2 = (im == 0) ? 0 : 3 - im;   // kperm = {0,2,1}, involution
      const int j2 = (jm == 0) ? 0 : 3 - jm;
      const int idx2 = ((n * 169 + (2 * xx + i2) * 13 + (2 * y + j2)) * 32) + o;

      float P[16], Wm[16];
      load16(posT2 + (size_t)idx2 * 16, P);
      load16(wbase + ((i2 * 3 + j2) * 32 + o) * 16, Wm);
      float ss = 0.f;
#pragma unroll
      for (int p = 0; p < 4; ++p)
#pragma unroll
        for (int r = 0; r < 4; ++r) {
          float v = Wm[p * 4 + 0] * P[0 + r] + Wm[p * 4 + 1] * P[4 + r] +
                    Wm[p * 4 + 2] * P[8 + r] + Wm[p * 4 + 3] * P[12 + r];
          float dv = v - mu[p * 4 + r];
          ss = fmaf(dv, dv, ss);
        }
      float ph = __expf(G - ss);
      // vote computed at permuted tap (i2,j2) belongs to slot ch=(i2*3+j2)*32+o?
      // No: votesE[ij] = votes[kperm(ij)] -> p at slot ij uses tap (i2,j2).
      // Here we computed the vote at tap (i2,j2) which is votesE of slot ijm.
      const int slot = ijm * 32 + o;
      p_hat[((size_t)sg * 32 + c) * 288 + slot] = ph;
      sPh[wave * 288 + slot] = ph;
    }
  }
  __syncthreads();
  // D reduce over block's 4 c + global atomic (8 c-grp blocks contribute)
  for (int t2 = threadIdx.x; t2 < 288; t2 += 256) {
    float s = sPh[t2] + sPh[288 + t2] + sPh[576 + t2] + sPh[864 + t2];
    int oo = t2 & 31, ij = t2 >> 5;
    int i = ij / 3, j = ij - i * 3;
    atomicAdd(Dwrite + ((size_t)n * 169 + (2 * xx + i) * 13 + (2 * y + j)) * 32 + oo, s);
  }
}

extern "C" void kernel_launch(void* const* d_in, const int* in_sizes, int n_in,
                              void* d_out, int out_size, void* d_ws,
                              size_t ws_size, hipStream_t stream) {
  const float* x   = (const float*)d_in[0];
  const float* Wt  = (const float*)d_in[1];
  const float* bv  = (const float*)d_in[2];
  const float* ba  = (const float*)d_in[3];
  const float* lam = (const float*)d_in[4];
  float* out = (float*)d_out;
  float* ws = (float*)d_ws;

  float* p_hat = ws + OFF_PHAT;
  float* D0    = ws + OFF_D0;
  float* D1    = ws + OFF_D1;
  float* posT2 = ws + OFF_POST;
  float* actT  = ws + OFF_ACTT;
  float* Wt2   = ws + OFF_WT2;

  (void)in_sizes; (void)n_in; (void)out_size; (void)ws_size;

  // fused prep: transposes + zero D0/D1 (D0,D1 contiguous in ws)
  prep_kernel<<<3787, 256, 0, stream>>>(x, Wt, posT2, actT, Wt2, D0);

  // M0 + E1 -> p_hat, D0
  em_kernel<<<2304, 256, 0, stream>>>(Wt2, posT2, actT, p_hat, D1, D0,
                                      bv, ba, lam, out, 0);
  // M1 (p_hat, D0) + E2 -> p_hat, D1
  em_kernel<<<2304, 256, 0, stream>>>(Wt2, posT2, actT, p_hat, D0, D1,
                                      bv, ba, lam, out, 1);
  // M2 (p_hat, D1) -> out
  em_kernel<<<2304, 256, 0, stream>>>(Wt2, posT2, actT, p_hat, D1, D0,
                                      bv, ba, lam, out, 2);
}

// Round 10
// 169.629 us; speedup vs baseline: 1.3519x; 1.3519x over previous
//
#include <hip/hip_runtime.h>

// ---------------------------------------------------------------------------
// ConvCaps (EM routing): b=8, B=32, C=32, K=3, stride=2, Win=13, Wout=6, 3 iters
// x: (8, 544, 13, 13) f32   [pose 512ch = (q,r,o), act 32ch]
// W: (3,3,32,32,4,4) f32    [ch=(ij*32+o)][c][p][q], 512 floats per ch
// out: (8, 544, 6, 6) f32
// vote[d=p*4+r] = sum_q W[ch][c][p][q] * pose[n,q,r,o, 2x+i, 2y+j]
//
// R10 = R8 structure (175 us best: LDS staging, (256,4), grid 2304) with the
// vote/accumulate/E-distance cores rewritten in ext_vector float2/float4 so
// the backend emits v_pk_fma_f32 (2 fp32 lanes/inst) and keeps fragments in
// v4f registers instead of float[16] arrays.
// Session rules learned: (256,3) always -> VGPR 84 + scratch spill (R5/R6/R9);
// (256,2)/(256,4) -> VGPR 60, no spill. W register cache (80 VGPR) -> spill.
// p_hat slices are block-private; only D crosses blocks -> ping-pong D0/D1.
// ---------------------------------------------------------------------------

typedef float v2f __attribute__((ext_vector_type(2)));
typedef float v4f __attribute__((ext_vector_type(4)));

// workspace layout (floats)
#define OFF_PHAT 0           // 288*32*288 = 2654208   [spatial][c][slot]
#define OFF_D0   2654208     // 43264 = 8*169*32   [n][pix][o]
#define OFF_D1   2697472     // 43264
#define OFF_POST 2740736     // 692224 = 8*32*169*16   [(n,o)][pix][d]
#define OFF_ACTT 3432960     // 43264  [n][pix][o]
#define OFF_WT2  3476224     // 147456 = 32*288*16  [c][ch][d]
// total 3623680 floats = 14.5 MB

__device__ __forceinline__ float wred64(float v) {
#pragma unroll
  for (int m = 32; m >= 1; m >>= 1) v += __shfl_xor(v, m, 64);
  return v;
}

__device__ __forceinline__ v2f lo2(v4f a) { return __builtin_shufflevector(a, a, 0, 1); }
__device__ __forceinline__ v2f hi2(v4f a) { return __builtin_shufflevector(a, a, 2, 3); }

// One fused prep kernel (range-branched elementwise):
//   [0,692224)        pose transpose -> posT[((n*32+o)*169+pix)*16 + d]
//   [692224,735488)   act transpose  -> actT[n][pix][o]
//   [735488,882944)   W transpose    -> Wt2[c][ch][d]
//   [882944,969472)   zero D0 and D1
__global__ __launch_bounds__(256) void prep_kernel(
    const float* __restrict__ x, const float* __restrict__ Wt,
    float* __restrict__ posT, float* __restrict__ actT,
    float* __restrict__ Wt2, float* __restrict__ Dz) {
  int tid = blockIdx.x * 256 + threadIdx.x;   // 969472 = 3787*256
  if (tid < 692224) {
    int pix = tid % 169; int t = tid / 169;
    int o = t & 31; t >>= 5;
    int d = t & 15; int n = t >> 4;
    float v = x[((size_t)n * 544 + d * 32 + o) * 169 + pix];
    posT[((size_t)(n * 32 + o) * 169 + pix) * 16 + d] = v;
  } else if (tid < 735488) {
    int r = tid - 692224;
    int pix = r % 169; int t = r / 169;
    int o = t & 31; int n = t >> 5;
    float v = x[(size_t)n * 91936 + 86528 + o * 169 + pix];
    actT[((size_t)n * 169 + pix) * 32 + o] = v;
  } else if (tid < 882944) {
    int r = tid - 735488;                     // 147456 = 32*288*16
    int c = r / 4608; int s = r - c * 4608;
    int ch = s >> 4, d = s & 15;
    Wt2[r] = Wt[(size_t)ch * 512 + c * 16 + d];
  } else {
    Dz[tid - 882944] = 0.f;                   // D0 then D1 (contiguous)
  }
}

// Fused EM step.
// mode 0: M(uniform Rp) + E -> p_hat, Dwrite
// mode 1: M(p_hat, Dread) + E -> p_hat, Dwrite
// mode 2: M(p_hat, Dread) -> final output
__global__ __launch_bounds__(256, 4) void em_kernel(
    const float* __restrict__ Wt2, const float* __restrict__ posT,
    const float* __restrict__ actT, float* __restrict__ p_hat,
    const float* __restrict__ Dread, float* __restrict__ Dwrite,
    const float* __restrict__ beta_v, const float* __restrict__ beta_a,
    const float* __restrict__ lambda_, float* __restrict__ out, int mode) {
  __shared__ float sP[288 * 20];   // pose patch, stride 20 (float4-aligned)
  __shared__ float sE[288];        // a/1152 or a/D per child slot
  __shared__ float sPh[4 * 288];   // per-wave p_hat by slot, for D reduce

  const int g = blockIdx.x & 7;        // c group
  const int sg = blockIdx.x >> 3;      // spatial 0..287
  const int wave = threadIdx.x >> 6;
  const int lane = threadIdx.x & 63;
  const int c = g * 4 + wave;

  int t = sg;
  const int y = t % 6; t /= 6;
  const int xx = t % 6;
  const int n = t / 6;

  const float bvv = beta_v[0], bav = beta_a[0], lamv = lambda_[0];
  const float* wbase = Wt2 + (size_t)c * 4608;

  // ---- prefetch p_hat (global, coalesced) so vmcnt overlaps staging ----
  float phv[5];
  if (mode != 0) {
    const float* phb = p_hat + ((size_t)sg * 32 + c) * 288;
#pragma unroll
    for (int k = 0; k < 5; ++k) {
      int ch = lane + 64 * k; if (ch > 287) ch = 287;
      phv[k] = phb[ch];
    }
  }

  // ---- stage pose patch (coalesced float4) ----
  for (int task = threadIdx.x; task < 1152; task += 256) {
    int ch = task >> 2, q = task & 3;
    int o = ch & 31, ij = ch >> 5;
    int i = ij / 3, j = ij - i * 3;
    int pix = (2 * xx + i) * 13 + (2 * y + j);
    v4f v = *(const v4f*)(posT +
        ((size_t)((n * 32 + o) * 169) + pix) * 16 + q * 4);
    *(v4f*)(sP + ch * 20 + q * 4) = v;
  }
  // ---- stage rhat scale: a/1152 or a/D (32-contiguous reads) ----
  for (int task = threadIdx.x; task < 288; task += 256) {
    int o = task & 31, ij = task >> 5;
    int i = ij / 3, j = ij - i * 3;
    int idx = ((size_t)n * 169 + (2 * xx + i) * 13 + (2 * y + j)) * 32 + o;
    float a = actT[idx];
    sE[task] = (mode == 0) ? a * (1.0f / 1152.0f) : a / Dread[idx];
  }
  __syncthreads();

  // ---- M step: packed float2 accumulation ----
  float sum_r = 0.f;
  v2f sv2[8], sq2[8];
#pragma unroll
  for (int d = 0; d < 8; ++d) { sv2[d] = 0.f; sq2[d] = 0.f; }

#pragma unroll
  for (int k = 0; k < 5; ++k) {
    int ch = lane + 64 * k;
    const bool act_l = (ch < 288);
    const int chm = act_l ? ch : 0;

    const v4f* Pp = (const v4f*)(sP + chm * 20);
    v4f P0 = Pp[0], P1 = Pp[1], P2 = Pp[2], P3 = Pp[3];
    const v4f* Wp = (const v4f*)(wbase + chm * 16);
    v4f W0 = Wp[0], W1 = Wp[1], W2 = Wp[2], W3 = Wp[3];

    float rhat = sE[chm];
    if (mode != 0) rhat *= phv[k];
    if (!act_l) rhat = 0.f;
    sum_r += rhat;

    v2f PL0 = lo2(P0), PH0 = hi2(P0), PL1 = lo2(P1), PH1 = hi2(P1);
    v2f PL2 = lo2(P2), PH2 = hi2(P2), PL3 = lo2(P3), PH3 = hi2(P3);
    v2f r2 = rhat;

#pragma unroll
    for (int p = 0; p < 4; ++p) {
      v4f Wr = (p == 0) ? W0 : (p == 1) ? W1 : (p == 2) ? W2 : W3;
      v2f vlo = Wr.x * PL0 + Wr.y * PL1 + Wr.z * PL2 + Wr.w * PL3;
      v2f vhi = Wr.x * PH0 + Wr.y * PH1 + Wr.z * PH2 + Wr.w * PH3;
      v2f tlo = r2 * vlo, thi = r2 * vhi;
      sv2[p * 2 + 0] += tlo;
      sv2[p * 2 + 1] += thi;
      sq2[p * 2 + 0] += tlo * vlo;
      sq2[p * 2 + 1] += thi * vhi;
    }
  }

  sum_r = wred64(sum_r);
  const float inv_sr = 1.0f / sum_r;
  float mu[16];
  float lsum = 0.f;
#pragma unroll
  for (int d = 0; d < 16; ++d) {
    float s1 = wred64(sv2[d >> 1][d & 1]);
    float s2 = wred64(sq2[d >> 1][d & 1]);
    float m = s1 * inv_sr;
    mu[d] = m;
    float sg_ = fmaxf(s2 * inv_sr - m * m, 1e-30f);
    lsum += __logf(sg_);
  }
  const float cost = (16.f * bvv + lsum) * sum_r;
  const float aout = 1.0f / (1.0f + __expf(-lamv * (bav - cost)));

  if (mode == 2) {
    if (lane == 0) {
      float* ob = out + (size_t)(n * 544 + c * 16) * 36 + xx * 6 + y;
#pragma unroll
      for (int d = 0; d < 16; ++d) ob[d * 36] = mu[d];
      out[(size_t)(n * 544 + 512 + c) * 36 + xx * 6 + y] = aout;
    }
    return;
  }

  // ---- E step: recompute votes (packed), store to kperm'd slot ----
  v2f mu2[8];
#pragma unroll
  for (int d = 0; d < 8; ++d) { mu2[d].x = mu[2 * d]; mu2[d].y = mu[2 * d + 1]; }
  const float G = __logf(aout) - 0.5f * (lsum + 16.f * 1.8378770664093453f);

#pragma unroll
  for (int k = 0; k < 5; ++k) {
    int mch = lane + 64 * k;
    if (mch < 288) {
      const v4f* Pp = (const v4f*)(sP + mch * 20);
      v4f P0 = Pp[0], P1 = Pp[1], P2 = Pp[2], P3 = Pp[3];
      const v4f* Wp = (const v4f*)(wbase + mch * 16);
      v4f W0 = Wp[0], W1 = Wp[1], W2 = Wp[2], W3 = Wp[3];

      v2f PL0 = lo2(P0), PH0 = hi2(P0), PL1 = lo2(P1), PH1 = hi2(P1);
      v2f PL2 = lo2(P2), PH2 = hi2(P2), PL3 = lo2(P3), PH3 = hi2(P3);
      v2f ss2 = 0.f;
#pragma unroll
      for (int p = 0; p < 4; ++p) {
        v4f Wr = (p == 0) ? W0 : (p == 1) ? W1 : (p == 2) ? W2 : W3;
        v2f vlo = Wr.x * PL0 + Wr.y * PL1 + Wr.z * PL2 + Wr.w * PL3;
        v2f vhi = Wr.x * PH0 + Wr.y * PH1 + Wr.z * PH2 + Wr.w * PH3;
        v2f dlo = vlo - mu2[p * 2 + 0];
        v2f dhi = vhi - mu2[p * 2 + 1];
        ss2 += dlo * dlo;
        ss2 += dhi * dhi;
      }
      float ss = ss2.x + ss2.y;
      float ph = __expf(G - ss);
      int o = mch & 31, ijm = mch >> 5;
      int im = ijm / 3, jm = ijm - im * 3;
      int i2 = (im == 0) ? 0 : 3 - im;   // kperm = {0,2,1}, involution
      int j2 = (jm == 0) ? 0 : 3 - jm;
      int slot = (i2 * 3 + j2) * 32 + o;
      p_hat[((size_t)sg * 32 + c) * 288 + slot] = ph;
      sPh[wave * 288 + slot] = ph;
    }
  }
  __syncthreads();
  // D reduce over block's 4 c + global atomic (8 c-grp blocks contribute)
  for (int t2 = threadIdx.x; t2 < 288; t2 += 256) {
    float s = sPh[t2] + sPh[288 + t2] + sPh[576 + t2] + sPh[864 + t2];
    int o = t2 & 31, ij = t2 >> 5;
    int i = ij / 3, j = ij - i * 3;
    atomicAdd(Dwrite + ((size_t)n * 169 + (2 * xx + i) * 13 + (2 * y + j)) * 32 + o, s);
  }
}

extern "C" void kernel_launch(void* const* d_in, const int* in_sizes, int n_in,
                              void* d_out, int out_size, void* d_ws,
                              size_t ws_size, hipStream_t stream) {
  const float* x   = (const float*)d_in[0];
  const float* Wt  = (const float*)d_in[1];
  const float* bv  = (const float*)d_in[2];
  const float* ba  = (const float*)d_in[3];
  const float* lam = (const float*)d_in[4];
  float* out = (float*)d_out;
  float* ws = (float*)d_ws;

  float* p_hat = ws + OFF_PHAT;
  float* D0    = ws + OFF_D0;
  float* D1    = ws + OFF_D1;
  float* posT  = ws + OFF_POST;
  float* actT  = ws + OFF_ACTT;
  float* Wt2   = ws + OFF_WT2;

  (void)in_sizes; (void)n_in; (void)out_size; (void)ws_size;

  // fused prep: transposes + zero D0/D1 (D0,D1 contiguous in ws)
  prep_kernel<<<3787, 256, 0, stream>>>(x, Wt, posT, actT, Wt2, D0);

  // M0 + E1 -> p_hat, D0
  em_kernel<<<2304, 256, 0, stream>>>(Wt2, posT, actT, p_hat, D1, D0,
                                      bv, ba, lam, out, 0);
  // M1 (p_hat, D0) + E2 -> p_hat, D1
  em_kernel<<<2304, 256, 0, stream>>>(Wt2, posT, actT, p_hat, D0, D1,
                                      bv, ba, lam, out, 1);
  // M2 (p_hat, D1) -> out
  em_kernel<<<2304, 256, 0, stream>>>(Wt2, posT, actT, p_hat, D1, D0,
                                      bv, ba, lam, out, 2);
}